// Round 1
// baseline (1519.075 us; speedup 1.0000x reference)
//
#include <hip/hip_runtime.h>

#define NPART 1024
#define NF    104      // 8 (tp0) + 32 (tp1) + 32 (tp2) + 32 (tp3)

__device__ __forceinline__ float softplus_f(float v) {
    // logaddexp(v, 0) = max(v,0) + log1p(exp(-|v|)); args here are tiny, fast path fine
    return fmaxf(v, 0.0f) + __logf(1.0f + __expf(-fabsf(v)));
}

// ---------------------------------------------------------------------------
// Fused pairwise kernel: computes tp0 features, tp1/tp2/tp3 chain per pair in
// registers; accumulates row sums (LDS atomics, conflict-free lane->row map)
// and col sums (thread-private registers). Never materializes tp.
// Block: 512 threads = 64 cols x 8 row-octets; tile = 64 rows x 64 cols.
// Grid: (16 rowTiles, 16 colTiles).
// ---------------------------------------------------------------------------
__global__ __launch_bounds__(512) void pair_kernel(
    const float* __restrict__ x,
    const float* __restrict__ tw0, const float* __restrict__ tb0,
    const float* __restrict__ tw,  const float* __restrict__ tb,
    float* __restrict__ ws_rs,     // [16 colTiles][1024 rows][NF]
    float* __restrict__ ws_cs)     // [16 rowTiles][1024 cols][NF]
{
    __shared__ float xs[64][4];
    __shared__ float rs[64][NF + 1];   // +1 pad: stride 105 -> conflict-free banks
    __shared__ float cm[64][NF];

    const int t = threadIdx.x;          // 0..511
    const int c = t >> 3;               // col within block: 0..63
    const int g = t & 7;                // row octet: 0..7
    const int rowTile = blockIdx.x;     // 0..15
    const int colTile = blockIdx.y;     // 0..15
    const int i0 = rowTile * 64;
    const int j  = colTile * 64 + c;

    for (int idx = t; idx < 64 * (NF + 1); idx += 512) ((float*)rs)[idx] = 0.0f;
    for (int idx = t; idx < 64 * NF;       idx += 512) ((float*)cm)[idx] = 0.0f;
    if (t < 64) {
        xs[t][0] = x[(i0 + t) * 3 + 0];
        xs[t][1] = x[(i0 + t) * 3 + 1];
        xs[t][2] = x[(i0 + t) * 3 + 2];
    }
    __syncthreads();

    const float xj0 = x[j * 3 + 0];
    const float xj1 = x[j * 3 + 1];
    const float xj2 = x[j * 3 + 2];
    const float A = 0.62831853071795864769f;   // 2*pi / L, L = 10

    float cs0[8], cs1[32], cs2[32], cs3[32];
    #pragma unroll
    for (int q = 0; q < 8; ++q) cs0[q] = 0.0f;
    #pragma unroll
    for (int q = 0; q < 32; ++q) { cs1[q] = 0.0f; cs2[q] = 0.0f; cs3[q] = 0.0f; }

    for (int k = 0; k < 8; ++k) {
        // lane->row map: within a wave (c in [8w,8w+8), g in [0,8)) rows are all
        // distinct -> ds_add atomics below are conflict-free
        const int r = g * 8 + ((c + k) & 7);
        const int i = i0 + r;

        float dx0 = xs[r][0] - xj0;
        float dx1 = xs[r][1] - xj1;
        float dx2 = xs[r][2] - xj2;
        float s0 = __sinf(A * dx0), s1 = __sinf(A * dx1), s2 = __sinf(A * dx2);
        float c0 = __cosf(A * dx0), c1 = __cosf(A * dx1), c2 = __cosf(A * dx2);
        float mask = (i == j) ? 0.0f : 1.0f;
        float dsn = mask * sqrtf(s0 * s0 + s1 * s1 + s2 * s2);
        float dcs = mask * sqrtf(c0 * c0 + c1 * c1 + c2 * c2);
        float f0[8] = {c0, c1, c2, s0, s1, s2, dsn, dcs};

        // tp0 sums
        #pragma unroll
        for (int q = 0; q < 8; ++q) { cs0[q] += f0[q]; atomicAdd(&rs[r][q], f0[q]); }

        // layer 1: 8 -> 32 (weights via uniform-index scalar loads)
        float tp[32];
        #pragma unroll
        for (int o = 0; o < 32; ++o) {
            float a = tb0[o];
            #pragma unroll
            for (int kk = 0; kk < 8; ++kk) a = fmaf(f0[kk], tw0[kk * 32 + o], a);
            tp[o] = softplus_f(a);
        }
        #pragma unroll
        for (int o = 0; o < 32; ++o) { cs1[o] += tp[o]; atomicAdd(&rs[r][8 + o], tp[o]); }

        // layer 2: 32 -> 32, residual
        float nx[32];
        #pragma unroll
        for (int o = 0; o < 32; ++o) {
            float a = tb[o];
            #pragma unroll
            for (int kk = 0; kk < 32; ++kk) a = fmaf(tp[kk], tw[kk * 32 + o], a);
            nx[o] = softplus_f(a);
        }
        #pragma unroll
        for (int o = 0; o < 32; ++o) {
            tp[o] += nx[o];
            cs2[o] += tp[o];
            atomicAdd(&rs[r][40 + o], tp[o]);
        }

        // layer 3: 32 -> 32, residual
        #pragma unroll
        for (int o = 0; o < 32; ++o) {
            float a = tb[32 + o];
            #pragma unroll
            for (int kk = 0; kk < 32; ++kk) a = fmaf(tp[kk], tw[1024 + kk * 32 + o], a);
            nx[o] = softplus_f(a);
        }
        #pragma unroll
        for (int o = 0; o < 32; ++o) {
            tp[o] += nx[o];
            cs3[o] += tp[o];
            atomicAdd(&rs[r][72 + o], tp[o]);
        }
    }

    // merge per-thread col sums (8 threads per col) into LDS
    #pragma unroll
    for (int q = 0; q < 8; ++q) atomicAdd(&cm[c][q], cs0[q]);
    #pragma unroll
    for (int q = 0; q < 32; ++q) {
        atomicAdd(&cm[c][8 + q],  cs1[q]);
        atomicAdd(&cm[c][40 + q], cs2[q]);
        atomicAdd(&cm[c][72 + q], cs3[q]);
    }
    __syncthreads();

    for (int idx = t; idx < 64 * NF; idx += 512) {
        int rr = idx / NF;
        int f  = idx - rr * NF;
        ws_rs[(colTile * NPART + i0 + rr) * NF + f]           = rs[rr][f];
        ws_cs[(rowTile * NPART + colTile * 64 + rr) * NF + f] = cm[rr][f];
    }
}

// Sum the 16 partials of each kind, convert to means (/1024).
__global__ void reduce_kernel(const float* __restrict__ ws_rs, const float* __restrict__ ws_cs,
                              float* __restrict__ Srow, float* __restrict__ Scol)
{
    int idx = blockIdx.x * 256 + threadIdx.x;
    if (idx >= NPART * NF) return;
    float a = 0.0f, b = 0.0f;
    #pragma unroll
    for (int s = 0; s < 16; ++s) {
        a += ws_rs[s * NPART * NF + idx];
        b += ws_cs[s * NPART * NF + idx];
    }
    Srow[idx] = a * (1.0f / 1024.0f);
    Scol[idx] = b * (1.0f / 1024.0f);
}

// layer 0: sp=0 so only tp0 mean features (W0 rows 9..24) contribute
__global__ __launch_bounds__(256) void sp_layer0_kernel(
    const float* __restrict__ w0, const float* __restrict__ b0,
    const float* __restrict__ Srow, const float* __restrict__ Scol,
    float* __restrict__ sp)
{
    int t = threadIdx.x;
    int r = blockIdx.x * 4 + (t >> 6);
    int o = t & 63;
    float a = b0[o];
    #pragma unroll
    for (int k = 0; k < 8; ++k) a = fmaf(Srow[r * NF + k], w0[(9 + k) * 64 + o], a);
    #pragma unroll
    for (int k = 0; k < 8; ++k) a = fmaf(Scol[r * NF + k], w0[(17 + k) * 64 + o], a);
    sp[r * 64 + o] = softplus_f(a);
}

// compute up/dn means of sp and fold them (+bias) into uvec[o]
__global__ __launch_bounds__(1024) void sp_prep_kernel(
    const float* __restrict__ sp, const float* __restrict__ W, const float* __restrict__ b,
    float* __restrict__ uvec)
{
    __shared__ float part[16][64];
    __shared__ float um[64], dm[64];
    int t = threadIdx.x;
    int f = t & 63, s = t >> 6;              // s: 16 row-chunks of 64
    float a = 0.0f;
    for (int rr = 0; rr < 64; ++rr) a += sp[(s * 64 + rr) * 64 + f];
    part[s][f] = a;
    __syncthreads();
    if (t < 128) {
        int ff = t & 63, grp = t >> 6;       // grp 0: rows 0..511 (up), 1: dn
        float m = 0.0f;
        #pragma unroll
        for (int q = 0; q < 8; ++q) m += part[grp * 8 + q][ff];
        m *= (1.0f / 512.0f);
        if (grp) dm[ff] = m; else um[ff] = m;
    }
    __syncthreads();
    if (t < 64) {
        float a2 = b[t];
        for (int k = 0; k < 64; ++k) a2 = fmaf(um[k], W[(64 + k) * 64 + t], a2);
        for (int k = 0; k < 64; ++k) a2 = fmaf(dm[k], W[(128 + k) * 64 + t], a2);
        uvec[t] = a2;
    }
}

// layers 1,2: sp_out = sp_in + softplus([sp,up,dn,trow,tcol] @ W + b)
__global__ __launch_bounds__(256) void sp_layer_kernel(
    const float* __restrict__ spin, const float* __restrict__ W,
    const float* __restrict__ uvec, const float* __restrict__ Srow,
    const float* __restrict__ Scol, int F0, float* __restrict__ spout)
{
    int t = threadIdx.x;
    int r = blockIdx.x * 4 + (t >> 6);
    int o = t & 63;
    float a = uvec[o];
    const float* sprow = spin + r * 64;
    #pragma unroll 8
    for (int k = 0; k < 64; ++k) a = fmaf(sprow[k], W[k * 64 + o], a);
    #pragma unroll 8
    for (int k = 0; k < 32; ++k) a = fmaf(Srow[r * NF + F0 + k], W[(192 + k) * 64 + o], a);
    #pragma unroll 8
    for (int k = 0; k < 32; ++k) a = fmaf(Scol[r * NF + F0 + k], W[(224 + k) * 64 + o], a);
    spout[r * 64 + o] = sprow[o] + softplus_f(a);
}

// final layer + fin projection + residual x
__global__ __launch_bounds__(256) void sp_final_kernel(
    const float* __restrict__ spin, const float* __restrict__ W,
    const float* __restrict__ uvec, const float* __restrict__ Srow,
    const float* __restrict__ Scol,
    const float* __restrict__ x, const float* __restrict__ finw, const float* __restrict__ finb,
    float* __restrict__ out)
{
    __shared__ float sb[4][64];
    int t = threadIdx.x;
    int ty = t >> 6, o = t & 63;
    int r = blockIdx.x * 4 + ty;
    float a = uvec[o];
    const float* sprow = spin + r * 64;
    #pragma unroll 8
    for (int k = 0; k < 64; ++k) a = fmaf(sprow[k], W[k * 64 + o], a);
    #pragma unroll 8
    for (int k = 0; k < 32; ++k) a = fmaf(Srow[r * NF + 72 + k], W[(192 + k) * 64 + o], a);
    #pragma unroll 8
    for (int k = 0; k < 32; ++k) a = fmaf(Scol[r * NF + 72 + k], W[(224 + k) * 64 + o], a);
    sb[ty][o] = sprow[o] + softplus_f(a);
    __syncthreads();
    if (t < 12) {
        int rr = t / 3, d = t - rr * 3;
        int row = blockIdx.x * 4 + rr;
        float acc = x[row * 3 + d] + finb[d];
        #pragma unroll
        for (int k = 0; k < 64; ++k) acc = fmaf(sb[rr][k], finw[k * 3 + d], acc);
        out[row * 3 + d] = acc;
    }
}

extern "C" void kernel_launch(void* const* d_in, const int* in_sizes, int n_in,
                              void* d_out, int out_size, void* d_ws, size_t ws_size,
                              hipStream_t stream)
{
    (void)in_sizes; (void)n_in; (void)out_size; (void)ws_size;
    const float* x     = (const float*)d_in[0];
    const float* sp_w0 = (const float*)d_in[1];
    const float* sp_b0 = (const float*)d_in[2];
    const float* sp_w  = (const float*)d_in[3];
    const float* sp_b  = (const float*)d_in[4];
    const float* tp_w0 = (const float*)d_in[5];
    const float* tp_b0 = (const float*)d_in[6];
    const float* tp_w  = (const float*)d_in[7];
    const float* tp_b  = (const float*)d_in[8];
    const float* fin_w = (const float*)d_in[9];
    const float* fin_b = (const float*)d_in[10];
    float* out = (float*)d_out;
    float* ws  = (float*)d_ws;

    float* ws_rs = ws;                               // 16*1024*104
    float* ws_cs = ws_rs + 16 * NPART * NF;          // 16*1024*104
    float* Srow  = ws_cs + 16 * NPART * NF;          // 1024*104 (means)
    float* Scol  = Srow + NPART * NF;                // 1024*104 (means)
    float* spA   = Scol + NPART * NF;                // 1024*64
    float* spB   = spA + NPART * 64;                 // 1024*64
    float* uvec  = spB + NPART * 64;                 // 64

    pair_kernel<<<dim3(16, 16), 512, 0, stream>>>(x, tp_w0, tp_b0, tp_w, tp_b, ws_rs, ws_cs);
    reduce_kernel<<<(NPART * NF + 255) / 256, 256, 0, stream>>>(ws_rs, ws_cs, Srow, Scol);
    sp_layer0_kernel<<<256, 256, 0, stream>>>(sp_w0, sp_b0, Srow, Scol, spA);

    sp_prep_kernel<<<1, 1024, 0, stream>>>(spA, sp_w + 0 * 256 * 64, sp_b + 0 * 64, uvec);
    sp_layer_kernel<<<256, 256, 0, stream>>>(spA, sp_w + 0 * 256 * 64, uvec, Srow, Scol, 8, spB);

    sp_prep_kernel<<<1, 1024, 0, stream>>>(spB, sp_w + 1 * 256 * 64, sp_b + 1 * 64, uvec);
    sp_layer_kernel<<<256, 256, 0, stream>>>(spB, sp_w + 1 * 256 * 64, uvec, Srow, Scol, 40, spA);

    sp_prep_kernel<<<1, 1024, 0, stream>>>(spA, sp_w + 2 * 256 * 64, sp_b + 2 * 64, uvec);
    sp_final_kernel<<<256, 256, 0, stream>>>(spA, sp_w + 2 * 256 * 64, uvec, Srow, Scol,
                                             x, fin_w, fin_b, out);
}

// Round 2
// 1410.738 us; speedup vs baseline: 1.0768x; 1.0768x over previous
//
#include <hip/hip_runtime.h>

#define NPART 1024
#define NF    104      // 8 (tp0) + 32 (tp1) + 32 (tp2) + 32 (tp3)

__device__ __forceinline__ float softplus_f(float v) {
    // logaddexp(v,0) = max(v,0) + log1p(exp(-|v|))
    return fmaxf(v, 0.0f) + __logf(1.0f + __expf(-fabsf(v)));
}

// ---------------------------------------------------------------------------
// Fused pairwise kernel, spill-free version.
// Tile: 32 rows x 64 cols. Block 512 threads: c = t>>3 (0..63), g = t&7.
// k-loop 0..3: r = g*4 + ((c+k)&3)  -> each (r,c) pair of tile exactly once.
// Row sums and col sums both accumulate via LDS ds_add (no per-thread
// accumulator arrays -> live set ~100 VGPRs, no scratch).
// Block epilogue: global atomicAdd into pre-zeroed Srow/Scol (scaled 1/1024).
// ---------------------------------------------------------------------------
__global__ __launch_bounds__(512, 4) void pair_kernel(
    const float* __restrict__ x,
    const float* __restrict__ tw0, const float* __restrict__ tb0,
    const float* __restrict__ tw,  const float* __restrict__ tb,
    float* __restrict__ Srow,      // [1024][NF] means (pre-zeroed)
    float* __restrict__ Scol)      // [1024][NF] means (pre-zeroed)
{
    __shared__ float xs[32][4];
    __shared__ float rs[32][NF + 1];   // stride 105: banks (9r+q)%32, 2-way max
    __shared__ float cm[64][NF + 1];

    const int t = threadIdx.x;          // 0..511
    const int c = t >> 3;               // col within tile: 0..63
    const int g = t & 7;                // row quad: 0..7
    const int rowTile = blockIdx.x;     // 0..31
    const int colTile = blockIdx.y;     // 0..15
    const int i0 = rowTile * 32;
    const int j  = colTile * 64 + c;

    for (int idx = t; idx < 32 * (NF + 1); idx += 512) ((float*)rs)[idx] = 0.0f;
    for (int idx = t; idx < 64 * (NF + 1); idx += 512) ((float*)cm)[idx] = 0.0f;
    if (t < 32) {
        xs[t][0] = x[(i0 + t) * 3 + 0];
        xs[t][1] = x[(i0 + t) * 3 + 1];
        xs[t][2] = x[(i0 + t) * 3 + 2];
    }
    __syncthreads();

    const float xj0 = x[j * 3 + 0];
    const float xj1 = x[j * 3 + 1];
    const float xj2 = x[j * 3 + 2];
    const float A = 0.62831853071795864769f;   // 2*pi / L, L = 10

    for (int k = 0; k < 4; ++k) {
        const int r = g * 4 + ((c + k) & 3);
        const int i = i0 + r;
        float* __restrict__ rrow = &rs[r][0];
        float* __restrict__ crow = &cm[c][0];

        float dx0 = xs[r][0] - xj0;
        float dx1 = xs[r][1] - xj1;
        float dx2 = xs[r][2] - xj2;
        float s0 = __sinf(A * dx0), s1 = __sinf(A * dx1), s2 = __sinf(A * dx2);
        float c0 = __cosf(A * dx0), c1 = __cosf(A * dx1), c2 = __cosf(A * dx2);
        float mask = (i == j) ? 0.0f : 1.0f;
        float dsn = mask * sqrtf(s0 * s0 + s1 * s1 + s2 * s2);
        float dcs = mask * sqrtf(c0 * c0 + c1 * c1 + c2 * c2);
        float f0[8] = {c0, c1, c2, s0, s1, s2, dsn, dcs};

        #pragma unroll
        for (int q = 0; q < 8; ++q) {
            atomicAdd(rrow + q, f0[q]);
            atomicAdd(crow + q, f0[q]);
        }

        // ---- layer 1: 8 -> 32 (kk-outer, float2 inner: packed fma + batched s_loads)
        float2 acc[16];
        const float2* tb02 = (const float2*)tb0;
        #pragma unroll
        for (int o2 = 0; o2 < 16; ++o2) acc[o2] = tb02[o2];
        #pragma unroll
        for (int kk = 0; kk < 8; ++kk) {
            const float tv = f0[kk];
            const float2* w2 = (const float2*)(tw0 + kk * 32);
            #pragma unroll
            for (int o2 = 0; o2 < 16; ++o2) {
                acc[o2].x = fmaf(tv, w2[o2].x, acc[o2].x);
                acc[o2].y = fmaf(tv, w2[o2].y, acc[o2].y);
            }
        }
        float tp[32];
        #pragma unroll
        for (int o2 = 0; o2 < 16; ++o2) {
            tp[2 * o2]     = softplus_f(acc[o2].x);
            tp[2 * o2 + 1] = softplus_f(acc[o2].y);
        }
        #pragma unroll
        for (int o = 0; o < 32; ++o) {
            atomicAdd(rrow + 8 + o, tp[o]);
            atomicAdd(crow + 8 + o, tp[o]);
        }

        // ---- layer 2: 32 -> 32, residual
        const float2* tb2 = (const float2*)tb;
        #pragma unroll
        for (int o2 = 0; o2 < 16; ++o2) acc[o2] = tb2[o2];
        #pragma unroll
        for (int kk = 0; kk < 32; ++kk) {
            const float tv = tp[kk];
            const float2* w2 = (const float2*)(tw + kk * 32);
            #pragma unroll
            for (int o2 = 0; o2 < 16; ++o2) {
                acc[o2].x = fmaf(tv, w2[o2].x, acc[o2].x);
                acc[o2].y = fmaf(tv, w2[o2].y, acc[o2].y);
            }
        }
        #pragma unroll
        for (int o2 = 0; o2 < 16; ++o2) {
            tp[2 * o2]     += softplus_f(acc[o2].x);
            tp[2 * o2 + 1] += softplus_f(acc[o2].y);
        }
        #pragma unroll
        for (int o = 0; o < 32; ++o) {
            atomicAdd(rrow + 40 + o, tp[o]);
            atomicAdd(crow + 40 + o, tp[o]);
        }

        // ---- layer 3: 32 -> 32, residual
        #pragma unroll
        for (int o2 = 0; o2 < 16; ++o2) acc[o2] = tb2[16 + o2];
        #pragma unroll
        for (int kk = 0; kk < 32; ++kk) {
            const float tv = tp[kk];
            const float2* w2 = (const float2*)(tw + 1024 + kk * 32);
            #pragma unroll
            for (int o2 = 0; o2 < 16; ++o2) {
                acc[o2].x = fmaf(tv, w2[o2].x, acc[o2].x);
                acc[o2].y = fmaf(tv, w2[o2].y, acc[o2].y);
            }
        }
        #pragma unroll
        for (int o2 = 0; o2 < 16; ++o2) {
            tp[2 * o2]     += softplus_f(acc[o2].x);
            tp[2 * o2 + 1] += softplus_f(acc[o2].y);
        }
        #pragma unroll
        for (int o = 0; o < 32; ++o) {
            atomicAdd(rrow + 72 + o, tp[o]);
            atomicAdd(crow + 72 + o, tp[o]);
        }
    }

    __syncthreads();
    const float sc = 1.0f / 1024.0f;
    for (int idx = t; idx < 32 * NF; idx += 512) {
        int rr = idx / NF, f = idx - rr * NF;
        atomicAdd(&Srow[(i0 + rr) * NF + f], rs[rr][f] * sc);
    }
    for (int idx = t; idx < 64 * NF; idx += 512) {
        int cc = idx / NF, f = idx - cc * NF;
        atomicAdd(&Scol[(colTile * 64 + cc) * NF + f], cm[cc][f] * sc);
    }
}

// layer 0: sp=0 so only tp0 mean features (W0 rows 9..24) contribute
__global__ __launch_bounds__(256) void sp_layer0_kernel(
    const float* __restrict__ w0, const float* __restrict__ b0,
    const float* __restrict__ Srow, const float* __restrict__ Scol,
    float* __restrict__ sp)
{
    int t = threadIdx.x;
    int r = blockIdx.x * 4 + (t >> 6);
    int o = t & 63;
    float a = b0[o];
    #pragma unroll
    for (int k = 0; k < 8; ++k) a = fmaf(Srow[r * NF + k], w0[(9 + k) * 64 + o], a);
    #pragma unroll
    for (int k = 0; k < 8; ++k) a = fmaf(Scol[r * NF + k], w0[(17 + k) * 64 + o], a);
    sp[r * 64 + o] = softplus_f(a);
}

// compute up/dn means of sp and fold them (+bias) into uvec[o]
__global__ __launch_bounds__(1024) void sp_prep_kernel(
    const float* __restrict__ sp, const float* __restrict__ W, const float* __restrict__ b,
    float* __restrict__ uvec)
{
    __shared__ float part[16][64];
    __shared__ float um[64], dm[64];
    int t = threadIdx.x;
    int f = t & 63, s = t >> 6;
    float a = 0.0f;
    for (int rr = 0; rr < 64; ++rr) a += sp[(s * 64 + rr) * 64 + f];
    part[s][f] = a;
    __syncthreads();
    if (t < 128) {
        int ff = t & 63, grp = t >> 6;
        float m = 0.0f;
        #pragma unroll
        for (int q = 0; q < 8; ++q) m += part[grp * 8 + q][ff];
        m *= (1.0f / 512.0f);
        if (grp) dm[ff] = m; else um[ff] = m;
    }
    __syncthreads();
    if (t < 64) {
        float a2 = b[t];
        for (int k = 0; k < 64; ++k) a2 = fmaf(um[k], W[(64 + k) * 64 + t], a2);
        for (int k = 0; k < 64; ++k) a2 = fmaf(dm[k], W[(128 + k) * 64 + t], a2);
        uvec[t] = a2;
    }
}

// layers 1,2: sp_out = sp_in + softplus([sp,up,dn,trow,tcol] @ W + b)
__global__ __launch_bounds__(256) void sp_layer_kernel(
    const float* __restrict__ spin, const float* __restrict__ W,
    const float* __restrict__ uvec, const float* __restrict__ Srow,
    const float* __restrict__ Scol, int F0, float* __restrict__ spout)
{
    int t = threadIdx.x;
    int r = blockIdx.x * 4 + (t >> 6);
    int o = t & 63;
    float a = uvec[o];
    const float* sprow = spin + r * 64;
    #pragma unroll 8
    for (int k = 0; k < 64; ++k) a = fmaf(sprow[k], W[k * 64 + o], a);
    #pragma unroll 8
    for (int k = 0; k < 32; ++k) a = fmaf(Srow[r * NF + F0 + k], W[(192 + k) * 64 + o], a);
    #pragma unroll 8
    for (int k = 0; k < 32; ++k) a = fmaf(Scol[r * NF + F0 + k], W[(224 + k) * 64 + o], a);
    spout[r * 64 + o] = sprow[o] + softplus_f(a);
}

// final layer + fin projection + residual x
__global__ __launch_bounds__(256) void sp_final_kernel(
    const float* __restrict__ spin, const float* __restrict__ W,
    const float* __restrict__ uvec, const float* __restrict__ Srow,
    const float* __restrict__ Scol,
    const float* __restrict__ x, const float* __restrict__ finw, const float* __restrict__ finb,
    float* __restrict__ out)
{
    __shared__ float sb[4][64];
    int t = threadIdx.x;
    int ty = t >> 6, o = t & 63;
    int r = blockIdx.x * 4 + ty;
    float a = uvec[o];
    const float* sprow = spin + r * 64;
    #pragma unroll 8
    for (int k = 0; k < 64; ++k) a = fmaf(sprow[k], W[k * 64 + o], a);
    #pragma unroll 8
    for (int k = 0; k < 32; ++k) a = fmaf(Srow[r * NF + 72 + k], W[(192 + k) * 64 + o], a);
    #pragma unroll 8
    for (int k = 0; k < 32; ++k) a = fmaf(Scol[r * NF + 72 + k], W[(224 + k) * 64 + o], a);
    sb[ty][o] = sprow[o] + softplus_f(a);
    __syncthreads();
    if (t < 12) {
        int rr = t / 3, d = t - rr * 3;
        int row = blockIdx.x * 4 + rr;
        float acc = x[row * 3 + d] + finb[d];
        #pragma unroll
        for (int k = 0; k < 64; ++k) acc = fmaf(sb[rr][k], finw[k * 3 + d], acc);
        out[row * 3 + d] = acc;
    }
}

extern "C" void kernel_launch(void* const* d_in, const int* in_sizes, int n_in,
                              void* d_out, int out_size, void* d_ws, size_t ws_size,
                              hipStream_t stream)
{
    (void)in_sizes; (void)n_in; (void)out_size; (void)ws_size;
    const float* x     = (const float*)d_in[0];
    const float* sp_w0 = (const float*)d_in[1];
    const float* sp_b0 = (const float*)d_in[2];
    const float* sp_w  = (const float*)d_in[3];
    const float* sp_b  = (const float*)d_in[4];
    const float* tp_w0 = (const float*)d_in[5];
    const float* tp_b0 = (const float*)d_in[6];
    const float* tp_w  = (const float*)d_in[7];
    const float* tp_b  = (const float*)d_in[8];
    const float* fin_w = (const float*)d_in[9];
    const float* fin_b = (const float*)d_in[10];
    float* out = (float*)d_out;
    float* ws  = (float*)d_ws;

    float* Srow = ws;                      // 1024*NF
    float* Scol = Srow + NPART * NF;       // 1024*NF
    float* spA  = Scol + NPART * NF;       // 1024*64
    float* spB  = spA + NPART * 64;        // 1024*64
    float* uvec = spB + NPART * 64;        // 64

    hipMemsetAsync(Srow, 0, 2 * NPART * NF * sizeof(float), stream);

    pair_kernel<<<dim3(32, 16), 512, 0, stream>>>(x, tp_w0, tp_b0, tp_w, tp_b, Srow, Scol);
    sp_layer0_kernel<<<256, 256, 0, stream>>>(sp_w0, sp_b0, Srow, Scol, spA);

    sp_prep_kernel<<<1, 1024, 0, stream>>>(spA, sp_w + 0 * 256 * 64, sp_b + 0 * 64, uvec);
    sp_layer_kernel<<<256, 256, 0, stream>>>(spA, sp_w + 0 * 256 * 64, uvec, Srow, Scol, 8, spB);

    sp_prep_kernel<<<1, 1024, 0, stream>>>(spB, sp_w + 1 * 256 * 64, sp_b + 1 * 64, uvec);
    sp_layer_kernel<<<256, 256, 0, stream>>>(spB, sp_w + 1 * 256 * 64, uvec, Srow, Scol, 40, spA);

    sp_prep_kernel<<<1, 1024, 0, stream>>>(spA, sp_w + 2 * 256 * 64, sp_b + 2 * 64, uvec);
    sp_final_kernel<<<256, 256, 0, stream>>>(spA, sp_w + 2 * 256 * 64, uvec, Srow, Scol,
                                             x, fin_w, fin_b, out);
}

// Round 3
// 1275.504 us; speedup vs baseline: 1.1910x; 1.1060x over previous
//
#include <hip/hip_runtime.h>

#define NPART 1024
#define NF    104      // 8 (tp0) + 32 (tp1) + 32 (tp2) + 32 (tp3)

__device__ __forceinline__ float softplus_f(float v) {
    // preacts here are tiny (|v| < ~1): plain form is numerically safe
    return __logf(1.0f + __expf(v));
}

// ---------------------------------------------------------------------------
// Fused pairwise kernel. Tile 64 rows x 64 cols, block 1024 thr (16 waves).
// lane l = t&63 -> col c = l;  wave w = t>>6;  k-step: r = (l + 4w + k) & 63.
// Within every wave-step: 64 distinct rows AND 64 distinct cols -> LDS
// ds_add_f32 atomics with zero same-address serialization, 2-way banks only.
// Live set ~100 VGPRs -> no spill at the 128-VGPR cap from launch_bounds(1024).
// Epilogue: plain stores of per-block partial sums to ws (16 sets each).
// ---------------------------------------------------------------------------
__global__ __launch_bounds__(1024) void pair_kernel(
    const float* __restrict__ x,
    const float* __restrict__ tw0, const float* __restrict__ tb0,
    const float* __restrict__ tw,  const float* __restrict__ tb,
    float* __restrict__ ws_rs,     // [16 colTiles][1024 rows][NF]
    float* __restrict__ ws_cs)     // [16 rowTiles][1024 cols][NF]
{
    __shared__ float xs[64][4];
    __shared__ float rs[64][NF + 1];   // stride 105: bank (9r+f)%32, 2-way max
    __shared__ float cm[64][NF + 1];

    const int t = threadIdx.x;          // 0..1023
    const int l = t & 63;               // lane = col within tile
    const int w = t >> 6;               // wave: 0..15
    const int rowTile = blockIdx.x;     // 0..15
    const int colTile = blockIdx.y;     // 0..15
    const int i0 = rowTile * 64;
    const int j  = colTile * 64 + l;

    for (int idx = t; idx < 64 * (NF + 1); idx += 1024) {
        ((float*)rs)[idx] = 0.0f;
        ((float*)cm)[idx] = 0.0f;
    }
    if (t < 64) {
        xs[t][0] = x[(i0 + t) * 3 + 0];
        xs[t][1] = x[(i0 + t) * 3 + 1];
        xs[t][2] = x[(i0 + t) * 3 + 2];
    }
    __syncthreads();

    const float xj0 = x[j * 3 + 0];
    const float xj1 = x[j * 3 + 1];
    const float xj2 = x[j * 3 + 2];
    const float A = 0.62831853071795864769f;   // 2*pi / L, L = 10

    #pragma unroll 1
    for (int k = 0; k < 4; ++k) {
        const int r = (l + 4 * w + k) & 63;

        float dx0 = xs[r][0] - xj0;
        float dx1 = xs[r][1] - xj1;
        float dx2 = xs[r][2] - xj2;
        float s0 = __sinf(A * dx0), s1 = __sinf(A * dx1), s2 = __sinf(A * dx2);
        float c0 = __cosf(A * dx0), c1 = __cosf(A * dx1), c2 = __cosf(A * dx2);
        float mask = (i0 + r == j) ? 0.0f : 1.0f;
        float dsn = mask * sqrtf(s0 * s0 + s1 * s1 + s2 * s2);
        float dcs = mask * sqrtf(c0 * c0 + c1 * c1 + c2 * c2);
        float f0[8] = {c0, c1, c2, s0, s1, s2, dsn, dcs};

        #pragma unroll
        for (int q = 0; q < 8; ++q) {
            atomicAdd(&rs[r][q], f0[q]);      // direct __shared__ -> ds_add_f32
            atomicAdd(&cm[l][q], f0[q]);
        }

        // ---- layer 1: 8 -> 32
        float2 acc[16];
        const float2* tb02 = (const float2*)tb0;
        #pragma unroll
        for (int o2 = 0; o2 < 16; ++o2) acc[o2] = tb02[o2];
        #pragma unroll
        for (int kk = 0; kk < 8; ++kk) {
            const float tv = f0[kk];
            const float2* w2 = (const float2*)(tw0 + kk * 32);
            #pragma unroll
            for (int o2 = 0; o2 < 16; ++o2) {
                acc[o2].x = fmaf(tv, w2[o2].x, acc[o2].x);
                acc[o2].y = fmaf(tv, w2[o2].y, acc[o2].y);
            }
        }
        float tp[32];
        #pragma unroll
        for (int o2 = 0; o2 < 16; ++o2) {
            tp[2 * o2]     = softplus_f(acc[o2].x);
            tp[2 * o2 + 1] = softplus_f(acc[o2].y);
        }
        #pragma unroll
        for (int o = 0; o < 32; ++o) {
            atomicAdd(&rs[r][8 + o], tp[o]);
            atomicAdd(&cm[l][8 + o], tp[o]);
        }

        // ---- layer 2: 32 -> 32, residual
        const float2* tb2 = (const float2*)tb;
        #pragma unroll
        for (int o2 = 0; o2 < 16; ++o2) acc[o2] = tb2[o2];
        #pragma unroll
        for (int kk = 0; kk < 32; ++kk) {
            const float tv = tp[kk];
            const float2* w2 = (const float2*)(tw + kk * 32);
            #pragma unroll
            for (int o2 = 0; o2 < 16; ++o2) {
                acc[o2].x = fmaf(tv, w2[o2].x, acc[o2].x);
                acc[o2].y = fmaf(tv, w2[o2].y, acc[o2].y);
            }
        }
        #pragma unroll
        for (int o2 = 0; o2 < 16; ++o2) {
            tp[2 * o2]     += softplus_f(acc[o2].x);
            tp[2 * o2 + 1] += softplus_f(acc[o2].y);
        }
        #pragma unroll
        for (int o = 0; o < 32; ++o) {
            atomicAdd(&rs[r][40 + o], tp[o]);
            atomicAdd(&cm[l][40 + o], tp[o]);
        }

        // ---- layer 3: 32 -> 32, residual
        #pragma unroll
        for (int o2 = 0; o2 < 16; ++o2) acc[o2] = tb2[16 + o2];
        #pragma unroll
        for (int kk = 0; kk < 32; ++kk) {
            const float tv = tp[kk];
            const float2* w2 = (const float2*)(tw + 1024 + kk * 32);
            #pragma unroll
            for (int o2 = 0; o2 < 16; ++o2) {
                acc[o2].x = fmaf(tv, w2[o2].x, acc[o2].x);
                acc[o2].y = fmaf(tv, w2[o2].y, acc[o2].y);
            }
        }
        #pragma unroll
        for (int o2 = 0; o2 < 16; ++o2) {
            tp[2 * o2]     += softplus_f(acc[o2].x);
            tp[2 * o2 + 1] += softplus_f(acc[o2].y);
        }
        #pragma unroll
        for (int o = 0; o < 32; ++o) {
            atomicAdd(&rs[r][72 + o], tp[o]);
            atomicAdd(&cm[l][72 + o], tp[o]);
        }
    }

    __syncthreads();
    for (int idx = t; idx < 64 * NF; idx += 1024) {
        int rr = idx / NF, f = idx - rr * NF;
        ws_rs[(colTile * NPART + i0 + rr) * NF + f]           = rs[rr][f];
        ws_cs[(rowTile * NPART + colTile * 64 + rr) * NF + f] = cm[rr][f];
    }
}

// Sum the 16 partials of each kind, convert to means (/1024).
__global__ void reduce_kernel(const float* __restrict__ ws_rs, const float* __restrict__ ws_cs,
                              float* __restrict__ Srow, float* __restrict__ Scol)
{
    int idx = blockIdx.x * 256 + threadIdx.x;
    if (idx >= NPART * NF) return;
    float a = 0.0f, b = 0.0f;
    #pragma unroll
    for (int s = 0; s < 16; ++s) {
        a += ws_rs[s * NPART * NF + idx];
        b += ws_cs[s * NPART * NF + idx];
    }
    Srow[idx] = a * (1.0f / 1024.0f);
    Scol[idx] = b * (1.0f / 1024.0f);
}

// layer 0: sp=0 so only tp0 mean features (W0 rows 9..24) contribute
__global__ __launch_bounds__(256) void sp_layer0_kernel(
    const float* __restrict__ w0, const float* __restrict__ b0,
    const float* __restrict__ Srow, const float* __restrict__ Scol,
    float* __restrict__ sp)
{
    int t = threadIdx.x;
    int r = blockIdx.x * 4 + (t >> 6);
    int o = t & 63;
    float a = b0[o];
    #pragma unroll
    for (int k = 0; k < 8; ++k) a = fmaf(Srow[r * NF + k], w0[(9 + k) * 64 + o], a);
    #pragma unroll
    for (int k = 0; k < 8; ++k) a = fmaf(Scol[r * NF + k], w0[(17 + k) * 64 + o], a);
    sp[r * 64 + o] = softplus_f(a);
}

// compute up/dn means of sp and fold them (+bias) into uvec[o]
__global__ __launch_bounds__(1024) void sp_prep_kernel(
    const float* __restrict__ sp, const float* __restrict__ W, const float* __restrict__ b,
    float* __restrict__ uvec)
{
    __shared__ float part[16][64];
    __shared__ float um[64], dm[64];
    int t = threadIdx.x;
    int f = t & 63, s = t >> 6;
    float a = 0.0f;
    for (int rr = 0; rr < 64; ++rr) a += sp[(s * 64 + rr) * 64 + f];
    part[s][f] = a;
    __syncthreads();
    if (t < 128) {
        int ff = t & 63, grp = t >> 6;
        float m = 0.0f;
        #pragma unroll
        for (int q = 0; q < 8; ++q) m += part[grp * 8 + q][ff];
        m *= (1.0f / 512.0f);
        if (grp) dm[ff] = m; else um[ff] = m;
    }
    __syncthreads();
    if (t < 64) {
        float a2 = b[t];
        for (int k = 0; k < 64; ++k) a2 = fmaf(um[k], W[(64 + k) * 64 + t], a2);
        for (int k = 0; k < 64; ++k) a2 = fmaf(dm[k], W[(128 + k) * 64 + t], a2);
        uvec[t] = a2;
    }
}

// layers 1,2: sp_out = sp_in + softplus([sp,up,dn,trow,tcol] @ W + b)
__global__ __launch_bounds__(256) void sp_layer_kernel(
    const float* __restrict__ spin, const float* __restrict__ W,
    const float* __restrict__ uvec, const float* __restrict__ Srow,
    const float* __restrict__ Scol, int F0, float* __restrict__ spout)
{
    int t = threadIdx.x;
    int r = blockIdx.x * 4 + (t >> 6);
    int o = t & 63;
    float a = uvec[o];
    const float* sprow = spin + r * 64;
    #pragma unroll 8
    for (int k = 0; k < 64; ++k) a = fmaf(sprow[k], W[k * 64 + o], a);
    #pragma unroll 8
    for (int k = 0; k < 32; ++k) a = fmaf(Srow[r * NF + F0 + k], W[(192 + k) * 64 + o], a);
    #pragma unroll 8
    for (int k = 0; k < 32; ++k) a = fmaf(Scol[r * NF + F0 + k], W[(224 + k) * 64 + o], a);
    spout[r * 64 + o] = sprow[o] + softplus_f(a);
}

// final layer + fin projection + residual x
__global__ __launch_bounds__(256) void sp_final_kernel(
    const float* __restrict__ spin, const float* __restrict__ W,
    const float* __restrict__ uvec, const float* __restrict__ Srow,
    const float* __restrict__ Scol,
    const float* __restrict__ x, const float* __restrict__ finw, const float* __restrict__ finb,
    float* __restrict__ out)
{
    __shared__ float sb[4][64];
    int t = threadIdx.x;
    int ty = t >> 6, o = t & 63;
    int r = blockIdx.x * 4 + ty;
    float a = uvec[o];
    const float* sprow = spin + r * 64;
    #pragma unroll 8
    for (int k = 0; k < 64; ++k) a = fmaf(sprow[k], W[k * 64 + o], a);
    #pragma unroll 8
    for (int k = 0; k < 32; ++k) a = fmaf(Srow[r * NF + 72 + k], W[(192 + k) * 64 + o], a);
    #pragma unroll 8
    for (int k = 0; k < 32; ++k) a = fmaf(Scol[r * NF + 72 + k], W[(224 + k) * 64 + o], a);
    sb[ty][o] = sprow[o] + softplus_f(a);
    __syncthreads();
    if (t < 12) {
        int rr = t / 3, d = t - rr * 3;
        int row = blockIdx.x * 4 + rr;
        float acc = x[row * 3 + d] + finb[d];
        #pragma unroll
        for (int k = 0; k < 64; ++k) acc = fmaf(sb[rr][k], finw[k * 3 + d], acc);
        out[row * 3 + d] = acc;
    }
}

extern "C" void kernel_launch(void* const* d_in, const int* in_sizes, int n_in,
                              void* d_out, int out_size, void* d_ws, size_t ws_size,
                              hipStream_t stream)
{
    (void)in_sizes; (void)n_in; (void)out_size; (void)ws_size;
    const float* x     = (const float*)d_in[0];
    const float* sp_w0 = (const float*)d_in[1];
    const float* sp_b0 = (const float*)d_in[2];
    const float* sp_w  = (const float*)d_in[3];
    const float* sp_b  = (const float*)d_in[4];
    const float* tp_w0 = (const float*)d_in[5];
    const float* tp_b0 = (const float*)d_in[6];
    const float* tp_w  = (const float*)d_in[7];
    const float* tp_b  = (const float*)d_in[8];
    const float* fin_w = (const float*)d_in[9];
    const float* fin_b = (const float*)d_in[10];
    float* out = (float*)d_out;
    float* ws  = (float*)d_ws;

    float* ws_rs = ws;                               // 16*1024*NF
    float* ws_cs = ws_rs + 16 * NPART * NF;          // 16*1024*NF
    float* Srow  = ws_cs + 16 * NPART * NF;          // 1024*NF (means)
    float* Scol  = Srow + NPART * NF;                // 1024*NF (means)
    float* spA   = Scol + NPART * NF;                // 1024*64
    float* spB   = spA + NPART * 64;                 // 1024*64
    float* uvec  = spB + NPART * 64;                 // 64

    pair_kernel<<<dim3(16, 16), 1024, 0, stream>>>(x, tp_w0, tp_b0, tp_w, tp_b, ws_rs, ws_cs);
    reduce_kernel<<<(NPART * NF + 255) / 256, 256, 0, stream>>>(ws_rs, ws_cs, Srow, Scol);
    sp_layer0_kernel<<<256, 256, 0, stream>>>(sp_w0, sp_b0, Srow, Scol, spA);

    sp_prep_kernel<<<1, 1024, 0, stream>>>(spA, sp_w + 0 * 256 * 64, sp_b + 0 * 64, uvec);
    sp_layer_kernel<<<256, 256, 0, stream>>>(spA, sp_w + 0 * 256 * 64, uvec, Srow, Scol, 8, spB);

    sp_prep_kernel<<<1, 1024, 0, stream>>>(spB, sp_w + 1 * 256 * 64, sp_b + 1 * 64, uvec);
    sp_layer_kernel<<<256, 256, 0, stream>>>(spB, sp_w + 1 * 256 * 64, uvec, Srow, Scol, 40, spA);

    sp_prep_kernel<<<1, 1024, 0, stream>>>(spA, sp_w + 2 * 256 * 64, sp_b + 2 * 64, uvec);
    sp_final_kernel<<<256, 256, 0, stream>>>(spA, sp_w + 2 * 256 * 64, uvec, Srow, Scol,
                                             x, fin_w, fin_b, out);
}

// Round 4
// 1244.581 us; speedup vs baseline: 1.2206x; 1.0248x over previous
//
#include <hip/hip_runtime.h>

#define NPART 1024
#define NF    104      // 8 (tp0) + 32 (tp1) + 32 (tp2) + 32 (tp3)

__device__ __forceinline__ float softplus_f(float v) {
    // preacts here are tiny (|v| < ~1): plain form is numerically safe
    return __logf(1.0f + __expf(v));
}

// ---------------------------------------------------------------------------
// Fused pairwise kernel. Tile 32 rows x 64 cols, block 512 thr (8 waves).
// lane l = t&63 -> col c = l;  wave w = t>>6 (0..7);  k-step 0..3:
//   r = (l + 4w + k) & 31   -> each (r,c) of the tile exactly once.
// LDS ds_add_f32 atomics: cm conflict-free, rs 2-way same-address (2 lanes/row).
// amdgpu_waves_per_eu(4,4) PINS the VGPR budget at 128 (launch_bounds' 2nd arg
// is only a minimum; rounds 1-3 all spilled because the heuristic chose 64).
// Epilogue: global atomicAdd into memset-zeroed Srow/Scol, scaled 1/1024.
// ---------------------------------------------------------------------------
__global__ __attribute__((amdgpu_flat_work_group_size(512, 512),
                          amdgpu_waves_per_eu(4, 4)))
void pair_kernel(
    const float* __restrict__ x,
    const float* __restrict__ tw0, const float* __restrict__ tb0,
    const float* __restrict__ tw,  const float* __restrict__ tb,
    float* __restrict__ Srow,      // [1024][NF] means (pre-zeroed)
    float* __restrict__ Scol)      // [1024][NF] means (pre-zeroed)
{
    __shared__ float4 xs[32];
    __shared__ float rs[32][NF + 1];   // stride 105: bank (9r+f)%32
    __shared__ float cm[64][NF + 1];

    const int t = threadIdx.x;          // 0..511
    const int l = t & 63;               // lane = col within tile
    const int w = t >> 6;               // wave: 0..7
    const int rowTile = blockIdx.x;     // 0..31
    const int colTile = blockIdx.y;     // 0..15
    const int i0 = rowTile * 32;
    const int j  = colTile * 64 + l;

    for (int idx = t; idx < 32 * (NF + 1); idx += 512) ((float*)rs)[idx] = 0.0f;
    for (int idx = t; idx < 64 * (NF + 1); idx += 512) ((float*)cm)[idx] = 0.0f;
    if (t < 32) {
        xs[t] = make_float4(x[(i0 + t) * 3 + 0], x[(i0 + t) * 3 + 1],
                            x[(i0 + t) * 3 + 2], 0.0f);
    }
    __syncthreads();

    const float xj0 = x[j * 3 + 0];
    const float xj1 = x[j * 3 + 1];
    const float xj2 = x[j * 3 + 2];
    const float A = 0.62831853071795864769f;   // 2*pi / L, L = 10

    #pragma unroll 1
    for (int k = 0; k < 4; ++k) {
        const int r = (l + 4 * w + k) & 31;

        float4 xi = xs[r];
        float dx0 = xi.x - xj0;
        float dx1 = xi.y - xj1;
        float dx2 = xi.z - xj2;
        float s0 = __sinf(A * dx0), s1 = __sinf(A * dx1), s2 = __sinf(A * dx2);
        float c0 = __cosf(A * dx0), c1 = __cosf(A * dx1), c2 = __cosf(A * dx2);
        float mask = (i0 + r == j) ? 0.0f : 1.0f;
        float dsn = mask * sqrtf(s0 * s0 + s1 * s1 + s2 * s2);
        float dcs = mask * sqrtf(c0 * c0 + c1 * c1 + c2 * c2);
        float f0[8] = {c0, c1, c2, s0, s1, s2, dsn, dcs};

        #pragma unroll
        for (int q = 0; q < 8; ++q) {
            atomicAdd(&rs[r][q], f0[q]);      // direct __shared__ -> ds_add_f32
            atomicAdd(&cm[l][q], f0[q]);
        }

        // ---- layer 1: 8 -> 32
        float2 acc[16];
        const float2* tb02 = (const float2*)tb0;
        #pragma unroll
        for (int o2 = 0; o2 < 16; ++o2) acc[o2] = tb02[o2];
        #pragma unroll
        for (int kk = 0; kk < 8; ++kk) {
            const float tv = f0[kk];
            const float2* w2 = (const float2*)(tw0 + kk * 32);
            #pragma unroll
            for (int o2 = 0; o2 < 16; ++o2) {
                acc[o2].x = fmaf(tv, w2[o2].x, acc[o2].x);
                acc[o2].y = fmaf(tv, w2[o2].y, acc[o2].y);
            }
        }
        float tp[32];
        #pragma unroll
        for (int o2 = 0; o2 < 16; ++o2) {
            tp[2 * o2]     = softplus_f(acc[o2].x);
            tp[2 * o2 + 1] = softplus_f(acc[o2].y);
        }
        #pragma unroll
        for (int o = 0; o < 32; ++o) {
            atomicAdd(&rs[r][8 + o], tp[o]);
            atomicAdd(&cm[l][8 + o], tp[o]);
        }

        // ---- layer 2: 32 -> 32, residual
        const float2* tb2 = (const float2*)tb;
        #pragma unroll
        for (int o2 = 0; o2 < 16; ++o2) acc[o2] = tb2[o2];
        #pragma unroll
        for (int kk = 0; kk < 32; ++kk) {
            const float tv = tp[kk];
            const float2* w2 = (const float2*)(tw + kk * 32);
            #pragma unroll
            for (int o2 = 0; o2 < 16; ++o2) {
                acc[o2].x = fmaf(tv, w2[o2].x, acc[o2].x);
                acc[o2].y = fmaf(tv, w2[o2].y, acc[o2].y);
            }
        }
        #pragma unroll
        for (int o2 = 0; o2 < 16; ++o2) {
            tp[2 * o2]     += softplus_f(acc[o2].x);
            tp[2 * o2 + 1] += softplus_f(acc[o2].y);
        }
        #pragma unroll
        for (int o = 0; o < 32; ++o) {
            atomicAdd(&rs[r][40 + o], tp[o]);
            atomicAdd(&cm[l][40 + o], tp[o]);
        }

        // ---- layer 3: 32 -> 32, residual
        #pragma unroll
        for (int o2 = 0; o2 < 16; ++o2) acc[o2] = tb2[16 + o2];
        #pragma unroll
        for (int kk = 0; kk < 32; ++kk) {
            const float tv = tp[kk];
            const float2* w2 = (const float2*)(tw + 1024 + kk * 32);
            #pragma unroll
            for (int o2 = 0; o2 < 16; ++o2) {
                acc[o2].x = fmaf(tv, w2[o2].x, acc[o2].x);
                acc[o2].y = fmaf(tv, w2[o2].y, acc[o2].y);
            }
        }
        #pragma unroll
        for (int o2 = 0; o2 < 16; ++o2) {
            tp[2 * o2]     += softplus_f(acc[o2].x);
            tp[2 * o2 + 1] += softplus_f(acc[o2].y);
        }
        #pragma unroll
        for (int o = 0; o < 32; ++o) {
            atomicAdd(&rs[r][72 + o], tp[o]);
            atomicAdd(&cm[l][72 + o], tp[o]);
        }
    }

    __syncthreads();
    const float sc = 1.0f / 1024.0f;
    for (int idx = t; idx < 32 * NF; idx += 512) {
        int rr = idx / NF, f = idx - rr * NF;
        atomicAdd(&Srow[(i0 + rr) * NF + f], rs[rr][f] * sc);
    }
    for (int idx = t; idx < 64 * NF; idx += 512) {
        int cc = idx / NF, f = idx - cc * NF;
        atomicAdd(&Scol[(colTile * 64 + cc) * NF + f], cm[cc][f] * sc);
    }
}

// layer 0: sp=0 so only tp0 mean features (W0 rows 9..24) contribute
__global__ __launch_bounds__(256) void sp_layer0_kernel(
    const float* __restrict__ w0, const float* __restrict__ b0,
    const float* __restrict__ Srow, const float* __restrict__ Scol,
    float* __restrict__ sp)
{
    int t = threadIdx.x;
    int r = blockIdx.x * 4 + (t >> 6);
    int o = t & 63;
    float a = b0[o];
    #pragma unroll
    for (int k = 0; k < 8; ++k) a = fmaf(Srow[r * NF + k], w0[(9 + k) * 64 + o], a);
    #pragma unroll
    for (int k = 0; k < 8; ++k) a = fmaf(Scol[r * NF + k], w0[(17 + k) * 64 + o], a);
    sp[r * 64 + o] = softplus_f(a);
}

// compute up/dn means of sp and fold them (+bias) into uvec[o]
__global__ __launch_bounds__(1024) void sp_prep_kernel(
    const float* __restrict__ sp, const float* __restrict__ W, const float* __restrict__ b,
    float* __restrict__ uvec)
{
    __shared__ float part[16][64];
    __shared__ float um[64], dm[64];
    int t = threadIdx.x;
    int f = t & 63, s = t >> 6;
    float a = 0.0f;
    for (int rr = 0; rr < 64; ++rr) a += sp[(s * 64 + rr) * 64 + f];
    part[s][f] = a;
    __syncthreads();
    if (t < 128) {
        int ff = t & 63, grp = t >> 6;
        float m = 0.0f;
        #pragma unroll
        for (int q = 0; q < 8; ++q) m += part[grp * 8 + q][ff];
        m *= (1.0f / 512.0f);
        if (grp) dm[ff] = m; else um[ff] = m;
    }
    __syncthreads();
    if (t < 64) {
        float a2 = b[t];
        for (int k = 0; k < 64; ++k) a2 = fmaf(um[k], W[(64 + k) * 64 + t], a2);
        for (int k = 0; k < 64; ++k) a2 = fmaf(dm[k], W[(128 + k) * 64 + t], a2);
        uvec[t] = a2;
    }
}

// layers 1,2: sp_out = sp_in + softplus([sp,up,dn,trow,tcol] @ W + b)
__global__ __launch_bounds__(256) void sp_layer_kernel(
    const float* __restrict__ spin, const float* __restrict__ W,
    const float* __restrict__ uvec, const float* __restrict__ Srow,
    const float* __restrict__ Scol, int F0, float* __restrict__ spout)
{
    int t = threadIdx.x;
    int r = blockIdx.x * 4 + (t >> 6);
    int o = t & 63;
    float a = uvec[o];
    const float* sprow = spin + r * 64;
    #pragma unroll 8
    for (int k = 0; k < 64; ++k) a = fmaf(sprow[k], W[k * 64 + o], a);
    #pragma unroll 8
    for (int k = 0; k < 32; ++k) a = fmaf(Srow[r * NF + F0 + k], W[(192 + k) * 64 + o], a);
    #pragma unroll 8
    for (int k = 0; k < 32; ++k) a = fmaf(Scol[r * NF + F0 + k], W[(224 + k) * 64 + o], a);
    spout[r * 64 + o] = sprow[o] + softplus_f(a);
}

// final layer + fin projection + residual x
__global__ __launch_bounds__(256) void sp_final_kernel(
    const float* __restrict__ spin, const float* __restrict__ W,
    const float* __restrict__ uvec, const float* __restrict__ Srow,
    const float* __restrict__ Scol,
    const float* __restrict__ x, const float* __restrict__ finw, const float* __restrict__ finb,
    float* __restrict__ out)
{
    __shared__ float sb[4][64];
    int t = threadIdx.x;
    int ty = t >> 6, o = t & 63;
    int r = blockIdx.x * 4 + ty;
    float a = uvec[o];
    const float* sprow = spin + r * 64;
    #pragma unroll 8
    for (int k = 0; k < 64; ++k) a = fmaf(sprow[k], W[k * 64 + o], a);
    #pragma unroll 8
    for (int k = 0; k < 32; ++k) a = fmaf(Srow[r * NF + 72 + k], W[(192 + k) * 64 + o], a);
    #pragma unroll 8
    for (int k = 0; k < 32; ++k) a = fmaf(Scol[r * NF + 72 + k], W[(224 + k) * 64 + o], a);
    sb[ty][o] = sprow[o] + softplus_f(a);
    __syncthreads();
    if (t < 12) {
        int rr = t / 3, d = t - rr * 3;
        int row = blockIdx.x * 4 + rr;
        float acc = x[row * 3 + d] + finb[d];
        #pragma unroll
        for (int k = 0; k < 64; ++k) acc = fmaf(sb[rr][k], finw[k * 3 + d], acc);
        out[row * 3 + d] = acc;
    }
}

extern "C" void kernel_launch(void* const* d_in, const int* in_sizes, int n_in,
                              void* d_out, int out_size, void* d_ws, size_t ws_size,
                              hipStream_t stream)
{
    (void)in_sizes; (void)n_in; (void)out_size; (void)ws_size;
    const float* x     = (const float*)d_in[0];
    const float* sp_w0 = (const float*)d_in[1];
    const float* sp_b0 = (const float*)d_in[2];
    const float* sp_w  = (const float*)d_in[3];
    const float* sp_b  = (const float*)d_in[4];
    const float* tp_w0 = (const float*)d_in[5];
    const float* tp_b0 = (const float*)d_in[6];
    const float* tp_w  = (const float*)d_in[7];
    const float* tp_b  = (const float*)d_in[8];
    const float* fin_w = (const float*)d_in[9];
    const float* fin_b = (const float*)d_in[10];
    float* out = (float*)d_out;
    float* ws  = (float*)d_ws;

    float* Srow = ws;                      // 1024*NF (means)
    float* Scol = Srow + NPART * NF;       // 1024*NF (means)
    float* spA  = Scol + NPART * NF;       // 1024*64
    float* spB  = spA + NPART * 64;        // 1024*64
    float* uvec = spB + NPART * 64;        // 64

    hipMemsetAsync(Srow, 0, 2 * NPART * NF * sizeof(float), stream);

    pair_kernel<<<dim3(32, 16), 512, 0, stream>>>(x, tp_w0, tp_b0, tp_w, tp_b, Srow, Scol);
    sp_layer0_kernel<<<256, 256, 0, stream>>>(sp_w0, sp_b0, Srow, Scol, spA);

    sp_prep_kernel<<<1, 1024, 0, stream>>>(spA, sp_w + 0 * 256 * 64, sp_b + 0 * 64, uvec);
    sp_layer_kernel<<<256, 256, 0, stream>>>(spA, sp_w + 0 * 256 * 64, uvec, Srow, Scol, 8, spB);

    sp_prep_kernel<<<1, 1024, 0, stream>>>(spB, sp_w + 1 * 256 * 64, sp_b + 1 * 64, uvec);
    sp_layer_kernel<<<256, 256, 0, stream>>>(spB, sp_w + 1 * 256 * 64, uvec, Srow, Scol, 40, spA);

    sp_prep_kernel<<<1, 1024, 0, stream>>>(spA, sp_w + 2 * 256 * 64, sp_b + 2 * 64, uvec);
    sp_final_kernel<<<256, 256, 0, stream>>>(spA, sp_w + 2 * 256 * 64, uvec, Srow, Scol,
                                             x, fin_w, fin_b, out);
}